// Round 8
// baseline (2322.821 us; speedup 1.0000x reference)
//
#include <hip/hip_runtime.h>
#include <math.h>

// Problem constants (fixed by the reference: H=1024, B=16, L=4, S=512)
#define Sv   512
#define Hv   1024
#define BSZ  16
#define NLB  4
#define NITEM 64          // BSZ*NLB
#define LOv  224          // >= max option len (512-300=212), multiple of 32
#define LDv  480          // >= max doc len (449), multiple of 32
#define NEGV (-1e30f)
#define VTHR (-1e20f)

typedef unsigned short u16;
typedef __attribute__((ext_vector_type(8))) short short8;   // 8 bf16 = 4 VGPRs (MFMA A/B frag)
using floatx4 = __attribute__((ext_vector_type(4))) float;

__device__ __forceinline__ u16 f2b(float x) {  // f32 -> bf16 RNE
  unsigned u = __float_as_uint(x);
  return (u16)((u + 0x7FFFu + ((u >> 16) & 1u)) >> 16);
}
__device__ __forceinline__ float b2f(u16 b) { return __uint_as_float(((unsigned)b) << 16); }

__device__ __forceinline__ float opt_view_f(const float* ll, const int* fp, int item, int t, int h) {
  int idx = fp[item] + t;
  return (idx < Sv) ? ll[((size_t)item * Sv + idx) * Hv + h] : 0.f;
}

// async global->LDS, 16B per lane; LDS dest = wave-uniform base + lane*16
__device__ __forceinline__ void gll16(const u16* g, u16* l) {
  __builtin_amdgcn_global_load_lds(
      (const __attribute__((address_space(1))) unsigned int*)(const void*)g,
      (__attribute__((address_space(3))) unsigned int*)(void*)l, 16, 0, 0);
}

// LDS chunk swizzle (BK=32 layout): row r's 16B chunk q lives at slot q ^ sw(r).
__device__ __forceinline__ int swz(int r) { return (r >> 1) & 3; }

// ======================= bf16 MFMA GEMM (attention-shaped, BK=32, piped dbuf) =======================
// Single-barrier pipelined K-loop: prefetch for tile k+1 is issued BEFORE computing tile k,
// so the vmcnt(0) drain at the next __syncthreads happens after a full compute phase of lead time.
enum { EP_BF16 = 0, EP_LOGIT = 1, EP_AS = 2 };
enum { IX_INST = 0, IX_ITQ = 1, IX_ITK = 2 };

struct MG {
  const u16* A; long long sA; int lda; int aidx;
  const u16* B; long long sB; int ldb; int bidx;
  float* C; long long sC; int ldc; int cidx;
  u16* Cb;
  const unsigned char* qmask; int ldqm;
  const unsigned char* kmask; int ldkm;
  const float* qlogv; int ldql;
  const float* klogv; int ldkl;
  int M, N, K, qi, kj, epi, pm;   // pm: pairmode (z = pair*BSZ + b, pair=i*3+jj)
};

__global__ __launch_bounds__(256) void mgemm(MG p) {
  __shared__ u16 As[2][128][32];
  __shared__ u16 Bs[2][128][32];
  int inst = blockIdx.z;
  int itq, itk;
  if (p.pm) {
    int b = inst % BSZ, pair = inst / BSZ;
    int i = pair / 3, jj = pair % 3;
    int j = jj + (jj >= i ? 1 : 0);
    itq = b * NLB + i; itk = b * NLB + j;
  } else {
    itq = (p.qi >= 0) ? inst * NLB + p.qi : inst;
    itk = (p.kj >= 0) ? inst * NLB + p.kj : inst;
  }
  int ai = (p.aidx == IX_ITQ) ? itq : (p.aidx == IX_ITK ? itk : inst);
  int bi = (p.bidx == IX_ITQ) ? itq : (p.bidx == IX_ITK ? itk : inst);
  int ci = (p.cidx == IX_ITQ) ? itq : (p.cidx == IX_ITK ? itk : inst);
  const u16* Ab = p.A + (size_t)ai * p.sA;
  const u16* Bb = p.B + (size_t)bi * p.sB;
  int tid = threadIdx.x;
  int m0 = blockIdx.y * 128, n0 = blockIdx.x * 128;
  int wave = tid >> 6, lane = tid & 63;
  int wm = (wave >> 1) * 64, wn = (wave & 1) * 64;
  int col = lane & 15, quad = lane >> 4;
  int rl = lane >> 2, cslot = lane & 3;
  floatx4 acc[4][4] = {};

  { // zero-init both buffers so never-staged boundary rows read as 0
    uint4 z4 = {0, 0, 0, 0};
    uint4* a4 = (uint4*)&As[0][0][0];
    uint4* b4 = (uint4*)&Bs[0][0][0];
    for (int z = tid; z < 1024; z += 256) { a4[z] = z4; b4[z] = z4; }
  }
  __syncthreads();

  int rb = wave * 32;
  int nk = p.K >> 5;
  // prologue: stage tile 0 into buffer 0
  #pragma unroll
  for (int c = 0; c < 2; c++) {
    int r = rb + c * 16 + rl;
    int gk = (cslot ^ swz(r)) * 8;
    if (m0 + r < p.M) gll16(Ab + (size_t)(m0 + r) * p.lda + gk, &As[0][rb + c * 16][0]);
    if (n0 + r < p.N) gll16(Bb + (size_t)(n0 + r) * p.ldb + gk, &Bs[0][rb + c * 16][0]);
  }
  int cur = 0;
  for (int ks = 0; ks < nk; ks++) {
    __syncthreads();   // drains prefetch for buf[cur] (vmcnt(0)+lgkmcnt(0)+barrier)
    if (ks + 1 < nk) {
      int k0 = (ks + 1) << 5;
      #pragma unroll
      for (int c = 0; c < 2; c++) {
        int r = rb + c * 16 + rl;
        int gk = k0 + ((cslot ^ swz(r)) * 8);
        if (m0 + r < p.M) gll16(Ab + (size_t)(m0 + r) * p.lda + gk, &As[cur ^ 1][rb + c * 16][0]);
        if (n0 + r < p.N) gll16(Bb + (size_t)(n0 + r) * p.ldb + gk, &Bs[cur ^ 1][rb + c * 16][0]);
      }
    }
    short8 a[4], b[4];
    #pragma unroll
    for (int mi = 0; mi < 4; mi++) {
      int r = wm + mi * 16 + col;
      a[mi] = *(const short8*)&As[cur][r][(quad ^ swz(r)) * 8];
    }
    #pragma unroll
    for (int ni = 0; ni < 4; ni++) {
      int r = wn + ni * 16 + col;
      b[ni] = *(const short8*)&Bs[cur][r][(quad ^ swz(r)) * 8];
    }
    #pragma unroll
    for (int mi = 0; mi < 4; mi++)
      #pragma unroll
      for (int ni = 0; ni < 4; ni++)
        acc[mi][ni] = __builtin_amdgcn_mfma_f32_16x16x32_bf16(a[mi], b[ni], acc[mi][ni], 0, 0, 0);
    cur ^= 1;
  }

  int sblk = (inst / BSZ) % 3;  // EP_AS: which a_s slot
  #pragma unroll
  for (int mi = 0; mi < 4; mi++) {
    #pragma unroll
    for (int ni = 0; ni < 4; ni++) {
      int n = n0 + wn + ni * 16 + col;
      if (n >= p.N) continue;
      #pragma unroll
      for (int r = 0; r < 4; r++) {
        int m = m0 + wm + mi * 16 + quad * 4 + r;
        if (m >= p.M) continue;
        float v = acc[mi][ni][r];
        if (p.epi == EP_BF16) {
          p.Cb[(size_t)ci * p.sC + (size_t)m * p.ldc + n] = f2b(v);
        } else if (p.epi == EP_AS) {
          u16* base = p.Cb + (size_t)itq * p.sC + (size_t)m * p.ldc;
          float cur2 = b2f(base[n]);  // compA block 0 = opt_enc
          base[(size_t)(1 + 2 * sblk) * Hv + n] = f2b(cur2 * v);
          base[(size_t)(2 + 2 * sblk) * Hv + n] = f2b(cur2 - v);
        } else {  // EP_LOGIT
          bool qm = p.qmask[itq * p.ldqm + m] != 0;
          bool km = p.kmask[itk * p.ldkm + n] != 0;
          p.C[(size_t)ci * p.sC + (size_t)m * p.ldc + n] =
            (qm && km) ? (v + p.qlogv[(size_t)itq * p.ldql + m] + p.klogv[(size_t)itk * p.ldkl + n]) : NEGV;
        }
      }
    }
  }
}

// ======================= FC GEMM (BK=32, piped dbuf): A [64][224][K] x weights [1024][K] ============
// Flat grid 1024 = 128 g x 8 nt, XCD-swizzled: id = g%8 + 8*(nt + 8*(g/8)) so all 8 n-tiles
// of one (inst, mtile) share an XCD (A-stripe served from that XCD's L2).
enum { FCE_TANH = 0, FCE_GATE = 1, FCE_SELFMAX = 2 };

struct MF {
  const u16* A; long long sA;   // lda = K
  const u16* B;                 // [1024][K]
  float* C; long long sC;       // f32 out [inst][224][1024]
  const float* bias;
  const float* ll; const int* fp; const float* Yv;   // gate
  const unsigned char* optm; float* outmax;          // selfmax
  int M, K, epi;
};

__global__ __launch_bounds__(256) void mgemm_fc(MF p) {
  __shared__ u16 As[2][128][32];
  __shared__ u16 Bs[2][128][32];
  int id = blockIdx.x;
  int low = id & 7, nt = (id >> 3) & 7, hi = id >> 6;
  int g = (hi << 3) | low;
  int inst = g >> 1, mt = g & 1;
  const u16* Ab = p.A + (size_t)inst * p.sA;
  int tid = threadIdx.x;
  int m0 = mt * 128, n0 = nt * 128;
  int wave = tid >> 6, lane = tid & 63;
  int wm = (wave >> 1) * 64, wn = (wave & 1) * 64;
  int col = lane & 15, quad = lane >> 4;
  int rl = lane >> 2, cslot = lane & 3;
  floatx4 acc[4][4] = {};

  { // zero-init both buffers so never-staged boundary rows read as 0
    uint4 z4 = {0, 0, 0, 0};
    uint4* a4 = (uint4*)&As[0][0][0];
    uint4* b4 = (uint4*)&Bs[0][0][0];
    for (int z = tid; z < 1024; z += 256) { a4[z] = z4; b4[z] = z4; }
  }
  __syncthreads();

  int rb = wave * 32;
  int nk = p.K >> 5;
  #pragma unroll
  for (int c = 0; c < 2; c++) {
    int r = rb + c * 16 + rl;
    int gk = (cslot ^ swz(r)) * 8;
    if (m0 + r < p.M) gll16(Ab + (size_t)(m0 + r) * p.K + gk, &As[0][rb + c * 16][0]);
    gll16(p.B + (size_t)(n0 + r) * p.K + gk, &Bs[0][rb + c * 16][0]);  // N=1024 always full
  }
  int cur = 0;
  for (int ks = 0; ks < nk; ks++) {
    __syncthreads();
    if (ks + 1 < nk) {
      int k0 = (ks + 1) << 5;
      #pragma unroll
      for (int c = 0; c < 2; c++) {
        int r = rb + c * 16 + rl;
        int gk = k0 + ((cslot ^ swz(r)) * 8);
        if (m0 + r < p.M) gll16(Ab + (size_t)(m0 + r) * p.K + gk, &As[cur ^ 1][rb + c * 16][0]);
        gll16(p.B + (size_t)(n0 + r) * p.K + gk, &Bs[cur ^ 1][rb + c * 16][0]);
      }
    }
    short8 a[4], b[4];
    #pragma unroll
    for (int mi = 0; mi < 4; mi++) {
      int r = wm + mi * 16 + col;
      a[mi] = *(const short8*)&As[cur][r][(quad ^ swz(r)) * 8];
    }
    #pragma unroll
    for (int ni = 0; ni < 4; ni++) {
      int r = wn + ni * 16 + col;
      b[ni] = *(const short8*)&Bs[cur][r][(quad ^ swz(r)) * 8];
    }
    #pragma unroll
    for (int mi = 0; mi < 4; mi++)
      #pragma unroll
      for (int ni = 0; ni < 4; ni++)
        acc[mi][ni] = __builtin_amdgcn_mfma_f32_16x16x32_bf16(a[mi], b[ni], acc[mi][ni], 0, 0, 0);
    cur ^= 1;
  }

  if (p.epi == FCE_SELFMAX) {
    // masked rows contribute 0 (safe: final max >= 0 since relu >= 0 and >=1 valid row/item)
    #pragma unroll
    for (int ni = 0; ni < 4; ni++) {
      int n = n0 + wn + ni * 16 + col;
      float bn = p.bias[n];
      float mloc = 0.f;
      #pragma unroll
      for (int mi = 0; mi < 4; mi++)
        #pragma unroll
        for (int r = 0; r < 4; r++) {
          int m = m0 + wm + mi * 16 + quad * 4 + r;
          float vv = fmaxf(acc[mi][ni][r] + bn, 0.f);
          if (m < p.M && p.optm[inst * LOv + m]) mloc = fmaxf(mloc, vv);
        }
      mloc = fmaxf(mloc, __shfl_xor(mloc, 16, 64));
      mloc = fmaxf(mloc, __shfl_xor(mloc, 32, 64));
      if (quad == 0)
        atomicMax((unsigned int*)(p.outmax + (size_t)inst * Hv + n), __float_as_uint(mloc));
    }
    return;
  }
  #pragma unroll
  for (int mi = 0; mi < 4; mi++) {
    #pragma unroll
    for (int ni = 0; ni < 4; ni++) {
      int n = n0 + wn + ni * 16 + col;
      #pragma unroll
      for (int r = 0; r < 4; r++) {
        int m = m0 + wm + mi * 16 + quad * 4 + r;
        if (m >= p.M) continue;
        float v = acc[mi][ni][r] + p.bias[n];
        float* cp = p.C + (size_t)inst * p.sC + (size_t)m * Hv + n;
        if (p.epi == FCE_TANH) {
          *cp = tanhf(v);
        } else {  // FCE_GATE
          float gg = 1.f / (1.f + __expf(-v));
          float xv = opt_view_f(p.ll, p.fp, inst, m, n);
          float yv = p.Yv[(size_t)inst * p.sC + (size_t)m * Hv + n];
          *cp = xv * gg + yv * (1.f - gg);
        }
      }
    }
  }
}

// ======================= helpers =======================
__global__ __launch_bounds__(256) void init_masks(const int* fp_in, const int* am, int* fp,
                                                  unsigned char* optm, unsigned char* docm) {
  int item = blockIdx.x;
  int f = fp_in[item];
  if (threadIdx.x == 0) fp[item] = f;
  for (int t = threadIdx.x; t < LDv; t += blockDim.x) {
    docm[item * LDv + t] = (t < f && t < Sv && am[item * Sv + t] > 0) ? 1 : 0;
    if (t < LOv) {
      int idx = f + t;
      optm[item * LOv + t] = (idx < Sv && am[item * Sv + idx] > 0) ? 1 : 0;
    }
  }
}

__global__ __launch_bounds__(256) void convf2b(const float* src, u16* dst, int n) {
  int i = blockIdx.x * 256 + threadIdx.x;
  int stride = gridDim.x * 256;
  for (; i < n; i += stride) dst[i] = f2b(src[i]);
}

// opt view -> compA block0 (ld 7H) + (opt*w3)
__global__ __launch_bounds__(256) void build_opt(const float* ll, const int* fp, const float* w3,
                                                 u16* compA0, u16* optw3B) {
  int t = blockIdx.x, item = blockIdx.y;
  int idx = fp[item] + t;
  bool v = idx < Sv;
  const float* src = ll + ((size_t)item * Sv + (v ? idx : 0)) * Hv;
  u16* d0 = compA0 + ((size_t)item * LOv + t) * (7 * Hv);
  u16* d1 = optw3B + ((size_t)item * LOv + t) * Hv;
  for (int h = threadIdx.x; h < Hv; h += 256) {
    float x = v ? src[h] : 0.f;
    d0[h] = f2b(x);
    d1[h] = f2b(x * w3[h]);
  }
}

__global__ __launch_bounds__(256) void build_doc(const float* ll, const unsigned char* docm, u16* docB) {
  int t = blockIdx.x, item = blockIdx.y;
  bool v = docm[item * LDv + t] != 0;
  const float* src = ll + ((size_t)item * Sv + (t < Sv ? t : 0)) * Hv;
  size_t o = ((size_t)item * LDv + t) * Hv;
  for (int h = threadIdx.x; h < Hv; h += 256) docB[o + h] = v ? f2b(src[h]) : (u16)0;
}

__global__ __launch_bounds__(256) void transpose_b(const float* src, long long sS,
                                                   const float* ll, const int* fp, const unsigned char* docm,
                                                   int mode, int Lt, u16* out) {
  __shared__ float tile[32][33];
  int t0 = blockIdx.x * 32, h0 = blockIdx.y * 32, item = blockIdx.z;
  int tx = threadIdx.x & 31, ty0 = threadIdx.x >> 5;
  for (int yy = ty0; yy < 32; yy += 8) {
    int t = t0 + yy, h = h0 + tx;
    float v = 0.f;
    if (t < Lt) {
      if (mode == 0)      v = src[(size_t)item * sS + (size_t)t * Hv + h];
      else if (mode == 1) { int idx = fp[item] + t; if (idx < Sv) v = ll[((size_t)item * Sv + idx) * Hv + h]; }
      else                { if (docm[item * LDv + t]) v = ll[((size_t)item * Sv + t) * Hv + h]; }
    }
    tile[yy][tx] = v;
  }
  __syncthreads();
  for (int yy = ty0; yy < 32; yy += 8) {
    int h = h0 + yy, t = t0 + tx;
    if (t < Lt) out[((size_t)item * Hv + h) * (size_t)Lt + t] = f2b(tile[tx][yy]);
  }
}

__global__ __launch_bounds__(256) void build_gateA(const float* ll, const int* fp, const float* corr, u16* gateA) {
  int t = blockIdx.x, item = blockIdx.y;
  int idx = fp[item] + t;
  bool v = idx < Sv;
  const float* src = ll + ((size_t)item * Sv + (v ? idx : 0)) * Hv;
  u16* dst = gateA + ((size_t)item * LOv + t) * (2 * Hv);
  const float* cr = corr + ((size_t)item * LOv + t) * Hv;
  for (int h = threadIdx.x; h < Hv; h += 256) {
    dst[h] = f2b(v ? src[h] : 0.f);
    dst[Hv + h] = f2b(cr[h]);
  }
}

__global__ __launch_bounds__(256) void conv_act(const float* src, const float* w3,
                                                u16* dst1, int ld1, u16* dstw3) {
  int t = blockIdx.x, item = blockIdx.y;
  const float* s = src + ((size_t)item * LOv + t) * Hv;
  u16* d1 = dst1 + ((size_t)item * LOv + t) * ld1;
  u16* d2 = dstw3 + ((size_t)item * LOv + t) * Hv;
  for (int h = threadIdx.x; h < Hv; h += 256) {
    float x = s[h];
    d1[h] = f2b(x);
    d2[h] = f2b(x * w3[h]);
  }
}

__global__ __launch_bounds__(256) void build_selfA23(u16* selfA) {
  int t = blockIdx.x, item = blockIdx.y;
  u16* row = selfA + ((size_t)item * LOv + t) * (4 * Hv);
  for (int h = threadIdx.x; h < Hv; h += 256) {
    float f = b2f(row[h]), a = b2f(row[Hv + h]);
    row[2 * Hv + h] = f2b(f * a);
    row[3 * Hv + h] = f2b(f - a);
  }
}

__global__ __launch_bounds__(256) void dot_rows(const float* src, long long sS,
                                                const float* ll, const int* fp, const unsigned char* docm,
                                                const float* w, float* outv, int ldo, int mode) {
  int t = blockIdx.x, item = blockIdx.y;
  int tid = threadIdx.x;
  float s = 0.f;
  for (int h = tid; h < Hv; h += 256) {
    float v;
    if (mode == 0)      v = src[(size_t)item * sS + (size_t)t * Hv + h];
    else if (mode == 1) v = opt_view_f(ll, fp, item, t, h);
    else                v = docm[item * LDv + t] ? ll[((size_t)item * Sv + t) * Hv + h] : 0.f;
    s += v * w[h];
  }
  __shared__ float red[4];
  for (int o = 32; o > 0; o >>= 1) s += __shfl_down(s, o, 64);
  int lane = tid & 63, wv = tid >> 6;
  if (lane == 0) red[wv] = s;
  __syncthreads();
  if (tid == 0) outv[(size_t)item * ldo + t] = red[0] + red[1] + red[2] + red[3];
}

__global__ __launch_bounds__(256) void row_softmax(const float* src, u16* dst, int Lk, int ldl, long long sL) {
  int m = blockIdx.x, inst = blockIdx.y;
  const float* row = src + (size_t)inst * sL + (size_t)m * ldl;
  u16* orow = dst + (size_t)inst * sL + (size_t)m * ldl;
  int tid = threadIdx.x;
  float mx = -INFINITY;
  for (int t = tid; t < Lk; t += 256) mx = fmaxf(mx, row[t]);
  __shared__ float sm[4]; __shared__ float ss[4];
  for (int o = 32; o > 0; o >>= 1) mx = fmaxf(mx, __shfl_down(mx, o, 64));
  int lane = tid & 63, wv = tid >> 6;
  if (lane == 0) sm[wv] = mx;
  __syncthreads();
  mx = fmaxf(fmaxf(sm[0], sm[1]), fmaxf(sm[2], sm[3]));
  float sum = 0.f;
  for (int t = tid; t < Lk; t += 256) sum += __expf(row[t] - mx);
  for (int o = 32; o > 0; o >>= 1) sum += __shfl_down(sum, o, 64);
  if (lane == 0) ss[wv] = sum;
  __syncthreads();
  sum = ss[0] + ss[1] + ss[2] + ss[3];
  float inv = 1.f / sum;
  for (int t = tid; t < Lk; t += 256) {
    float x = row[t];
    orow[t] = (x < VTHR) ? (u16)0 : f2b(__expf(x - mx) * inv);
  }
}

__global__ __launch_bounds__(256) void col_softmax(const float* src, u16* dst, int Mr, int ldl, long long sL) {
  int c = blockIdx.x, inst = blockIdx.y;
  const float* base = src + (size_t)inst * sL + c;
  u16* ob = dst + (size_t)inst * sL + c;
  int tid = threadIdx.x;
  float mx = -INFINITY;
  for (int t = tid; t < Mr; t += 256) mx = fmaxf(mx, base[(size_t)t * ldl]);
  __shared__ float sm[4]; __shared__ float ss[4];
  for (int o = 32; o > 0; o >>= 1) mx = fmaxf(mx, __shfl_down(mx, o, 64));
  int lane = tid & 63, wv = tid >> 6;
  if (lane == 0) sm[wv] = mx;
  __syncthreads();
  mx = fmaxf(fmaxf(sm[0], sm[1]), fmaxf(sm[2], sm[3]));
  float sum = 0.f;
  for (int t = tid; t < Mr; t += 256) sum += __expf(base[(size_t)t * ldl] - mx);
  for (int o = 32; o > 0; o >>= 1) sum += __shfl_down(sum, o, 64);
  if (lane == 0) ss[wv] = sum;
  __syncthreads();
  sum = ss[0] + ss[1] + ss[2] + ss[3];
  float inv = 1.f / sum;
  for (int t = tid; t < Mr; t += 256) {
    float x = base[(size_t)t * ldl];
    ob[(size_t)t * ldl] = (x < VTHR) ? (u16)0 : f2b(__expf(x - mx) * inv);
  }
}

// ======================= launch =======================
extern "C" void kernel_launch(void* const* d_in, const int* in_sizes, int n_in,
                              void* d_out, int out_size, void* d_ws, size_t ws_size,
                              hipStream_t stream) {
  const float* ll        = (const float*)d_in[0];
  const int* am          = (const int*)d_in[1];
  const int* fp_in       = (const int*)d_in[2];   // harness delivers int64 ref input as int32
  const float* attn_w1   = (const float*)d_in[4];
  const float* attn_w2   = (const float*)d_in[5];
  const float* attn_w3   = (const float*)d_in[6];
  const float* opt_w1    = (const float*)d_in[7];
  const float* opt_w2    = (const float*)d_in[8];
  const float* opt_w3    = (const float*)d_in[9];
  const float* self_w1   = (const float*)d_in[10];
  const float* self_w2   = (const float*)d_in[11];
  const float* self_w3   = (const float*)d_in[12];
  const float* attn_fc_w = (const float*)d_in[13];
  const float* attn_fc_b = (const float*)d_in[14];
  const float* comp_fc_w = (const float*)d_in[15];
  const float* comp_fc_b = (const float*)d_in[16];
  const float* gate_fc_w = (const float*)d_in[17];
  const float* gate_fc_b = (const float*)d_in[18];
  const float* self_fc_w = (const float*)d_in[19];
  const float* self_fc_b = (const float*)d_in[20];
  float* out = (float*)d_out;

  // ---- arena ----
  const size_t BIGF = (size_t)NITEM * LOv * Hv;          // 14,680,064
  float* optcorrF = (float*)d_ws;                        // later aliased as fusion
  float* optionF  = optcorrF + BIGF;
  float* logitF   = optionF + BIGF;
  float* qlog     = logitF + BIGF;
  float* klog     = qlog + (size_t)NITEM * LOv;
  float* optq     = klog + (size_t)NITEM * LDv;
  float* optk     = optq + (size_t)NITEM * LOv;
  u16* wcomp = (u16*)(optk + (size_t)NITEM * LOv);       // 1024*7168
  u16* wgate = wcomp + (size_t)Hv * 7 * Hv;
  u16* wattn = wgate + (size_t)Hv * 2 * Hv;
  u16* wself = wattn + (size_t)Hv * 3 * Hv;
  u16* kqB   = wself + (size_t)Hv * 4 * Hv;              // 64*224*480
  u16* awbB  = kqB + (size_t)NITEM * LOv * LDv;
  u16* cowB  = awbB + (size_t)NITEM * LOv * LDv;
  unsigned char* optm = (unsigned char*)(cowB + (size_t)NITEM * LOv * LOv);
  unsigned char* docm = optm + (size_t)NITEM * LOv;
  int* fp = (int*)(docm + (size_t)NITEM * LDv);
  u16* U = (u16*)(fp + NITEM + 32);
  const size_t E_OPT = (size_t)NITEM * LOv * Hv;
  const size_t E_DOC = (size_t)NITEM * LDv * Hv;
  // P1: compA [64][224][7168]; block0 doubles as opt_enc bf16
  u16* optw3B = U;
  u16* optTB  = U + E_OPT;
  u16* aw1B   = U + 2 * E_OPT;                           // 192*224*224
  u16* compA  = aw1B + (size_t)12 * BSZ * LOv * LOv;     // 64*224*7168
  // P2
  u16* gateA  = U;                                       // 64*224*2048
  // P3
  u16* docB   = U;
  u16* docTB  = U + E_DOC;
  u16* optw3C = U + 2 * E_DOC;
  u16* optTC  = optw3C + E_OPT;
  u16* attnA  = optTC + E_OPT;                           // 64*224*3072
  // P4
  u16* selfA  = U;                                       // 64*224*4096
  u16* fusw3  = U + (size_t)NITEM * LOv * 4 * Hv;
  u16* fusTB  = fusw3 + E_OPT;
  float* fusionF = optcorrF;

  const long long sOH = (long long)LOv * Hv;
  const long long sLL = (long long)LOv * LOv;
  const long long sLD = (long long)LOv * LDv;
  const long long sC7 = (long long)LOv * 7 * Hv;

  (void)hipMemsetAsync(d_out, 0, (size_t)NITEM * Hv * sizeof(float), stream);
  init_masks<<<NITEM, 256, 0, stream>>>(fp_in, am, fp, optm, docm);
  convf2b<<<1024, 256, 0, stream>>>(comp_fc_w, wcomp, Hv * 7 * Hv);
  convf2b<<<1024, 256, 0, stream>>>(gate_fc_w, wgate, Hv * 2 * Hv);
  convf2b<<<1024, 256, 0, stream>>>(attn_fc_w, wattn, Hv * 3 * Hv);
  convf2b<<<1024, 256, 0, stream>>>(self_fc_w, wself, Hv * 4 * Hv);
  build_opt<<<dim3(LOv, NITEM), 256, 0, stream>>>(ll, fp, opt_w3, compA, optw3B);
  transpose_b<<<dim3(LOv / 32, Hv / 32, NITEM), 256, 0, stream>>>(nullptr, 0, ll, fp, docm, 1, LOv, optTB);
  dot_rows<<<dim3(LOv, NITEM), 256, 0, stream>>>(nullptr, 0, ll, fp, docm, opt_w1, optq, LOv, 1);
  dot_rows<<<dim3(LOv, NITEM), 256, 0, stream>>>(nullptr, 0, ll, fp, docm, opt_w2, optk, LOv, 1);

  // ========== Phase 1: all 12 pairwise logits -> softmax -> a_s (fused into compA) ==========
  { // logits for all (i,j) pairs: z = pair*16 + b ; B = compA block0 (opt_enc)
    MG p = {};
    p.A = optw3B; p.sA = sOH; p.lda = Hv; p.aidx = IX_ITQ;
    p.B = compA;  p.sB = sC7; p.ldb = 7 * Hv; p.bidx = IX_ITK;
    p.C = logitF; p.sC = sLL; p.ldc = LOv; p.cidx = IX_INST;
    p.qmask = optm; p.ldqm = LOv; p.kmask = optm; p.ldkm = LOv;
    p.qlogv = optq; p.ldql = LOv; p.klogv = optk; p.ldkl = LOv;
    p.M = LOv; p.N = LOv; p.K = Hv; p.epi = EP_LOGIT; p.pm = 1;
    mgemm<<<dim3(2, 2, 12 * BSZ), 256, 0, stream>>>(p);
  }
  row_softmax<<<dim3(LOv, 12 * BSZ), 256, 0, stream>>>(logitF, aw1B, LOv, LOv, sLL);
  { // a_s = aw @ opt_enc[j]; epilogue writes cur*a, cur-a into compA blocks (1+2s, 2+2s)
    MG p = {};
    p.A = aw1B; p.sA = sLL; p.lda = LOv; p.aidx = IX_INST;
    p.B = optTB; p.sB = (long long)Hv * LOv; p.ldb = LOv; p.bidx = IX_ITK;
    p.Cb = compA; p.sC = sC7; p.ldc = 7 * Hv; p.cidx = IX_ITQ;
    p.M = LOv; p.N = Hv; p.K = LOv; p.epi = EP_AS; p.pm = 1;
    mgemm<<<dim3(8, 2, 12 * BSZ), 256, 0, stream>>>(p);
  }
  { // opt_corr = tanh(compA @ comp_w^T + b), all 64 insts in one launch
    MF p = {};
    p.A = compA; p.sA = sC7; p.B = wcomp;
    p.C = optcorrF; p.sC = sOH; p.bias = comp_fc_b;
    p.M = LOv; p.K = 7 * Hv; p.epi = FCE_TANH;
    mgemm_fc<<<1024, 256, 0, stream>>>(p);
  }

  // ========== Phase 2: gate FC + blend ==========
  build_gateA<<<dim3(LOv, NITEM), 256, 0, stream>>>(ll, fp, optcorrF, gateA);
  {
    MF p = {};
    p.A = gateA; p.sA = (long long)LOv * 2 * Hv; p.B = wgate;
    p.C = optionF; p.sC = sOH; p.bias = gate_fc_b;
    p.ll = ll; p.fp = fp; p.Yv = optcorrF;
    p.M = LOv; p.K = 2 * Hv; p.epi = FCE_GATE;
    mgemm_fc<<<1024, 256, 0, stream>>>(p);
  }

  // ========== Phase 3: doc attention + co-attention + attn FC ==========
  build_doc<<<dim3(LDv, NITEM), 256, 0, stream>>>(ll, docm, docB);
  transpose_b<<<dim3(LDv / 32, Hv / 32, NITEM), 256, 0, stream>>>(nullptr, 0, ll, fp, docm, 2, LDv, docTB);
  conv_act<<<dim3(LOv, NITEM), 256, 0, stream>>>(optionF, attn_w3, attnA, 3 * Hv, optw3C);
  transpose_b<<<dim3(LOv / 32, Hv / 32, NITEM), 256, 0, stream>>>(optionF, sOH, ll, fp, docm, 0, LOv, optTC);
  dot_rows<<<dim3(LOv, NITEM), 256, 0, stream>>>(optionF, sOH, ll, fp, docm, attn_w1, qlog, LOv, 0);
  dot_rows<<<dim3(LDv, NITEM), 256, 0, stream>>>(nullptr, 0, ll, fp, docm, attn_w2, klog, LDv, 2);
  { // logit [224,480]
    MG p = {};
    p.A = optw3C; p.sA = sOH; p.lda = Hv; p.aidx = IX_INST;
    p.B = docB; p.sB = (long long)LDv * Hv; p.ldb = Hv; p.bidx = IX_INST;
    p.C = logitF; p.sC = sLD; p.ldc = LDv; p.cidx = IX_INST;
    p.qmask = optm; p.ldqm = LOv; p.kmask = docm; p.ldkm = LDv;
    p.qlogv = qlog; p.ldql = LOv; p.klogv = klog; p.ldkl = LDv;
    p.M = LOv; p.N = LDv; p.K = Hv; p.qi = -1; p.kj = -1; p.epi = EP_LOGIT;
    mgemm<<<dim3(4, 2, NITEM), 256, 0, stream>>>(p);
  }
  row_softmax<<<dim3(LOv, NITEM), 256, 0, stream>>>(logitF, awbB, LDv, LDv, sLD);
  col_softmax<<<dim3(LDv, NITEM), 256, 0, stream>>>(logitF, kqB, LOv, LDv, sLD);
  { // attn = aw @ doc -> attnA block 1
    MG p = {};
    p.A = awbB; p.sA = sLD; p.lda = LDv; p.aidx = IX_INST;
    p.B = docTB; p.sB = (long long)Hv * LDv; p.ldb = LDv; p.bidx = IX_INST;
    p.Cb = attnA + Hv; p.sC = (long long)LOv * 3 * Hv; p.ldc = 3 * Hv; p.cidx = IX_INST;
    p.M = LOv; p.N = Hv; p.K = LDv; p.qi = -1; p.kj = -1; p.epi = EP_BF16;
    mgemm<<<dim3(8, 2, NITEM), 256, 0, stream>>>(p);
  }
  { // co_w = aw @ kq^T
    MG p = {};
    p.A = awbB; p.sA = sLD; p.lda = LDv; p.aidx = IX_INST;
    p.B = kqB; p.sB = sLD; p.ldb = LDv; p.bidx = IX_INST;
    p.Cb = cowB; p.sC = sLL; p.ldc = LOv; p.cidx = IX_INST;
    p.M = LOv; p.N = LOv; p.K = LDv; p.qi = -1; p.kj = -1; p.epi = EP_BF16;
    mgemm<<<dim3(2, 2, NITEM), 256, 0, stream>>>(p);
  }
  { // coattn = co_w @ option -> attnA block 2
    MG p = {};
    p.A = cowB; p.sA = sLL; p.lda = LOv; p.aidx = IX_INST;
    p.B = optTC; p.sB = (long long)Hv * LOv; p.ldb = LOv; p.bidx = IX_INST;
    p.Cb = attnA + 2 * Hv; p.sC = (long long)LOv * 3 * Hv; p.ldc = 3 * Hv; p.cidx = IX_INST;
    p.M = LOv; p.N = Hv; p.K = LOv; p.qi = -1; p.kj = -1; p.epi = EP_BF16;
    mgemm<<<dim3(8, 2, NITEM), 256, 0, stream>>>(p);
  }
  { // fusion = tanh(attnA @ attn_w^T + b)
    MF p = {};
    p.A = attnA; p.sA = (long long)LOv * 3 * Hv; p.B = wattn;
    p.C = fusionF; p.sC = sOH; p.bias = attn_fc_b;
    p.M = LOv; p.K = 3 * Hv; p.epi = FCE_TANH;
    mgemm_fc<<<1024, 256, 0, stream>>>(p);
  }

  // ========== Phase 4: self attention + self FC + masked max ==========
  conv_act<<<dim3(LOv, NITEM), 256, 0, stream>>>(fusionF, self_w3, selfA, 4 * Hv, fusw3);
  transpose_b<<<dim3(LOv / 32, Hv / 32, NITEM), 256, 0, stream>>>(fusionF, sOH, ll, fp, docm, 0, LOv, fusTB);
  dot_rows<<<dim3(LOv, NITEM), 256, 0, stream>>>(fusionF, sOH, ll, fp, docm, self_w1, qlog, LOv, 0);
  dot_rows<<<dim3(LOv, NITEM), 256, 0, stream>>>(fusionF, sOH, ll, fp, docm, self_w2, klog, LOv, 0);
  { // self logit (B = selfA block 0 = fusion bf16, ldb=4096)
    MG p = {};
    p.A = fusw3; p.sA = sOH; p.lda = Hv; p.aidx = IX_INST;
    p.B = selfA; p.sB = (long long)LOv * 4 * Hv; p.ldb = 4 * Hv; p.bidx = IX_INST;
    p.C = logitF; p.sC = sLL; p.ldc = LOv; p.cidx = IX_INST;
    p.qmask = optm; p.ldqm = LOv; p.kmask = optm; p.ldkm = LOv;
    p.qlogv = qlog; p.ldql = LOv; p.klogv = klog; p.ldkl = LOv;
    p.M = LOv; p.N = LOv; p.K = Hv; p.qi = -1; p.kj = -1; p.epi = EP_LOGIT;
    mgemm<<<dim3(2, 2, NITEM), 256, 0, stream>>>(p);
  }
  row_softmax<<<dim3(LOv, NITEM), 256, 0, stream>>>(logitF, awbB, LOv, LOv, sLL);
  { // attn2 = aw @ fusion -> selfA block 1
    MG p = {};
    p.A = awbB; p.sA = sLL; p.lda = LOv; p.aidx = IX_INST;
    p.B = fusTB; p.sB = (long long)Hv * LOv; p.ldb = LOv; p.bidx = IX_INST;
    p.Cb = selfA + Hv; p.sC = (long long)LOv * 4 * Hv; p.ldc = 4 * Hv; p.cidx = IX_INST;
    p.M = LOv; p.N = Hv; p.K = LOv; p.qi = -1; p.kj = -1; p.epi = EP_BF16;
    mgemm<<<dim3(8, 2, NITEM), 256, 0, stream>>>(p);
  }
  build_selfA23<<<dim3(LOv, NITEM), 256, 0, stream>>>(selfA);
  { // out[item,h] = max over valid t of relu(selfA @ self_w^T + b)
    MF p = {};
    p.A = selfA; p.sA = (long long)LOv * 4 * Hv; p.B = wself;
    p.bias = self_fc_b; p.optm = optm; p.outmax = out;
    p.M = LOv; p.K = 4 * Hv; p.epi = FCE_SELFMAX;
    mgemm_fc<<<1024, 256, 0, stream>>>(p);
  }
}